// Round 1
// baseline (348.269 us; speedup 1.0000x reference)
//
#include <hip/hip_runtime.h>

// SelfAttention: x(8,2048,768) fp32, W_q/W_k/W_v (768,768) fp32.
// Q=xWq^T K=xWk^T V=xWv^T; S=QK^T/sqrt(768); A=softmax(S); H=AV -> fp32 out.
// Strategy: f16 MFMA (fp32 accum) everywhere; unfused pipeline via workspace.

typedef _Float16 f16;
typedef __attribute__((ext_vector_type(8))) _Float16 f16x8;
typedef __attribute__((ext_vector_type(4))) _Float16 f16x4;
typedef __attribute__((ext_vector_type(4))) float    f32x4;

#define BM 128
#define BN 128
#define BK 32

// Problem constants
#define SEQ   2048
#define DIM   768
#define NBAT  8
#define MTOT  (NBAT * SEQ)            // 16384
#define XN    (MTOT * DIM)            // 12582912 elems
#define WN    (DIM * DIM)             // 589824
#define SB    (SEQ * (long)SEQ)       // 4194304 per-batch score elems
#define QB    ((long)SEQ * DIM)       // 1572864 per-batch Q/K/Vt elems

__device__ __forceinline__ void async_cp16(const void* g, void* l) {
  __builtin_amdgcn_global_load_lds((__attribute__((address_space(1))) void*)g,
                                   (__attribute__((address_space(3))) void*)l,
                                   16, 0, 0);
}

// fp32 -> f16 conversion, 4 elems/thread
__global__ void cvt_kernel(const float* __restrict__ in, f16* __restrict__ out, int n4) {
  int i = blockIdx.x * blockDim.x + threadIdx.x;
  if (i < n4) {
    float4 v = ((const float4*)in)[i];
    f16x4 o = {(f16)v.x, (f16)v.y, (f16)v.z, (f16)v.w};
    ((f16x4*)out)[i] = o;
  }
}

// NT GEMM: C[m][n] = sum_k A[m][k]*B[n][k], A rows stride K, B rows stride K.
// MODE 0: QKV projection. z in {0,1,2} selects weight/output. z<2 -> f16
//         row-major (ldc=N). z==2 -> f16 transposed per-batch (Vt[b][d][s]).
// MODE 1: f16 row-major with scale (scores).
// MODE 2: fp32 row-major (final H).
template <int MODE>
__global__ __launch_bounds__(256, 2)
void gemm_nt(const f16* __restrict__ Abase, long sAz,
             const f16* __restrict__ Bbase, long sBz,
             void* __restrict__ Cbase, long sCz,
             int N, int K, float scale)
{
  __shared__ f16 lA[BM * BK];   // [m][k], k contiguous (32 halfs = 64B/row)
  __shared__ f16 lB[BN * BK];

  const int tid = threadIdx.x;
  const int z   = blockIdx.z;
  const int m0  = blockIdx.x * BM;
  const int n0  = blockIdx.y * BN;

  const f16* A = Abase + (long)z * sAz;
  const f16* B = Bbase + (long)z * sBz;

  const int wave = tid >> 6;
  const int lane = tid & 63;
  const int wm = (wave & 1) * 64;
  const int wn = (wave >> 1) * 64;

  const f32x4 vzero = {0.f, 0.f, 0.f, 0.f};
  f32x4 acc[4][4];
#pragma unroll
  for (int i = 0; i < 4; ++i)
#pragma unroll
    for (int j = 0; j < 4; ++j) acc[i][j] = vzero;

  // staging: thread t loads 16B: row = t>>2 (stride-K rows), chunk = t&3.
  // LDS dest = base + lane*16 (HW constraint of global_load_lds).
  const int srow = tid >> 2;
  const int scol = (tid & 3) * 8;
  const f16* ga0 = A + (long)(m0 + srow) * K + scol;
  const f16* ga1 = A + (long)(m0 + 64 + srow) * K + scol;
  const f16* gb0 = B + (long)(n0 + srow) * K + scol;
  const f16* gb1 = B + (long)(n0 + 64 + srow) * K + scol;
  f16* la = &lA[tid * 8];
  f16* lb = &lB[tid * 8];

  // MFMA fragment addressing: A[m=lane&15][k=(lane>>4)*8 + 0..7] (16B contig)
  const int frow = lane & 15;
  const int fkb  = (lane >> 4) * 8;

  for (int k0 = 0; k0 < K; k0 += BK) {
    async_cp16(ga0 + k0, la);
    async_cp16(ga1 + k0, la + 64 * BK);
    async_cp16(gb0 + k0, lb);
    async_cp16(gb1 + k0, lb + 64 * BK);
    __syncthreads();   // drains vmcnt (compiler emits waitcnt before barrier)

    f16x8 af[4], bf[4];
#pragma unroll
    for (int i = 0; i < 4; ++i)
      af[i] = *(const f16x8*)&lA[(wm + i * 16 + frow) * BK + fkb];
#pragma unroll
    for (int j = 0; j < 4; ++j)
      bf[j] = *(const f16x8*)&lB[(wn + j * 16 + frow) * BK + fkb];
#pragma unroll
    for (int i = 0; i < 4; ++i)
#pragma unroll
      for (int j = 0; j < 4; ++j)
        acc[i][j] = __builtin_amdgcn_mfma_f32_16x16x32_f16(af[i], bf[j], acc[i][j], 0, 0, 0);
    __syncthreads();
  }

  // C/D layout: n = lane&15, m = (lane>>4)*4 + reg  [verified m89/m91]
  const int cn = lane & 15;
  const int cm = (lane >> 4) * 4;
#pragma unroll
  for (int i = 0; i < 4; ++i) {
#pragma unroll
    for (int j = 0; j < 4; ++j) {
      const int mm = m0 + wm + i * 16 + cm;
      const int nn = n0 + wn + j * 16 + cn;
      if constexpr (MODE == 2) {
        float* C = (float*)Cbase + (long)z * sCz;
#pragma unroll
        for (int r = 0; r < 4; ++r)
          C[(long)(mm + r) * N + nn] = acc[i][j][r];
      } else if constexpr (MODE == 1) {
        f16* C = (f16*)Cbase + (long)z * sCz;
#pragma unroll
        for (int r = 0; r < 4; ++r)
          C[(long)(mm + r) * N + nn] = (f16)(acc[i][j][r] * scale);
      } else {
        if (z < 2) {
          f16* C = (f16*)Cbase + (long)z * sCz;
#pragma unroll
          for (int r = 0; r < 4; ++r)
            C[(long)(mm + r) * N + nn] = (f16)acc[i][j][r];
        } else {
          // V transposed: Vt[b][d=nn][s=mm%SEQ], 4 contiguous s per lane
          f16* Vt = (f16*)Cbase + 2L * sCz;
          const int b  = mm >> 11;         // mm / 2048
          const int ml = mm & 2047;
          f16x4 t = {(f16)acc[i][j][0], (f16)acc[i][j][1],
                     (f16)acc[i][j][2], (f16)acc[i][j][3]};
          *(f16x4*)&Vt[(long)b * QB + (long)nn * SEQ + ml] = t;
        }
      }
    }
  }
}

// Row softmax in place on f16 scores; one 256-thread block per row of 2048.
__global__ __launch_bounds__(256)
void softmax_kernel(f16* __restrict__ S) {
  const long row = blockIdx.x;
  f16* p = S + row * SEQ;
  const int tid  = threadIdx.x;
  const int wave = tid >> 6;
  const int lane = tid & 63;

  f16x8 v = *(const f16x8*)(p + tid * 8);
  float f[8];
  float mx = -1e30f;
#pragma unroll
  for (int r = 0; r < 8; ++r) { f[r] = (float)v[r]; mx = fmaxf(mx, f[r]); }
#pragma unroll
  for (int o = 32; o > 0; o >>= 1) mx = fmaxf(mx, __shfl_xor(mx, o, 64));

  __shared__ float smax[4], ssum[4];
  if (lane == 0) smax[wave] = mx;
  __syncthreads();
  mx = fmaxf(fmaxf(smax[0], smax[1]), fmaxf(smax[2], smax[3]));

  float s = 0.f;
#pragma unroll
  for (int r = 0; r < 8; ++r) { f[r] = __expf(f[r] - mx); s += f[r]; }
#pragma unroll
  for (int o = 32; o > 0; o >>= 1) s += __shfl_xor(s, o, 64);
  if (lane == 0) ssum[wave] = s;
  __syncthreads();
  s = ssum[0] + ssum[1] + ssum[2] + ssum[3];

  const float inv = 1.f / s;
#pragma unroll
  for (int r = 0; r < 8; ++r) v[r] = (f16)(f[r] * inv);
  *(f16x8*)(p + tid * 8) = v;
}

extern "C" void kernel_launch(void* const* d_in, const int* in_sizes, int n_in,
                              void* d_out, int out_size, void* d_ws, size_t ws_size,
                              hipStream_t stream) {
  const float* x  = (const float*)d_in[0];
  const float* Wq = (const float*)d_in[1];
  const float* Wk = (const float*)d_in[2];
  const float* Wv = (const float*)d_in[3];

  // workspace layout (halfs): x16 | W16[3] | Q16 | K16 | Vt16 | S16
  f16* ws   = (f16*)d_ws;
  f16* x16  = ws;                         // XN
  f16* W16  = x16 + XN;                   // 3*WN (contiguous Wq,Wk,Wv)
  f16* QKV  = W16 + 3 * (long)WN;         // Q16, K16, Vt16: 3*XN
  f16* Q16  = QKV;
  f16* K16  = QKV + (long)XN;
  f16* Vt16 = QKV + 2L * XN;
  f16* S16  = QKV + 3L * XN;              // NBAT*SEQ*SEQ

  // 1. convert inputs to f16
  cvt_kernel<<<XN / 4 / 256, 256, 0, stream>>>(x, x16, XN / 4);
  cvt_kernel<<<WN / 4 / 256, 256, 0, stream>>>(Wq, W16, WN / 4);
  cvt_kernel<<<WN / 4 / 256, 256, 0, stream>>>(Wk, W16 + WN, WN / 4);
  cvt_kernel<<<WN / 4 / 256, 256, 0, stream>>>(Wv, W16 + 2 * WN, WN / 4);

  dim3 blk(256);
  // 2. QKV projections: M=16384, N=768, K=768; z selects weight; V -> Vt
  gemm_nt<0><<<dim3(MTOT / BM, DIM / BN, 3), blk, 0, stream>>>(
      x16, 0L, W16, (long)WN, (void*)QKV, (long)XN, DIM, DIM, 1.0f);
  // 3. scores: per batch M=N=2048, K=768, scale 1/sqrt(768), f16 out
  gemm_nt<1><<<dim3(SEQ / BM, SEQ / BN, NBAT), blk, 0, stream>>>(
      Q16, QB, K16, QB, (void*)S16, SB, SEQ, DIM, 0.03608439182435161f);
  // 4. softmax rows in place
  softmax_kernel<<<NBAT * SEQ, 256, 0, stream>>>(S16);
  // 5. H = P @ Vt^T: per batch M=2048, N=768, K=2048, fp32 out
  gemm_nt<2><<<dim3(SEQ / BM, DIM / BN, NBAT), blk, 0, stream>>>(
      S16, SB, Vt16, QB, d_out, QB, DIM, SEQ, 1.0f);
}

// Round 2
// 339.815 us; speedup vs baseline: 1.0249x; 1.0249x over previous
//
#include <hip/hip_runtime.h>

// SelfAttention: x(8,2048,768) fp32, W_q/W_k/W_v (768,768) fp32 -> H fp32.
// f16 MFMA pipeline, fused softmax:
//   cvt -> gemm<0> Q,K -> gemm<3> Vt -> gemm<1> P'=exp(S/sqrt(D)) -> gemm<2> H=P'V/rowsum
// All GEMMs: 128x128 tile, BK=64, XOR-swizzled LDS, global_load_lds(16B),
// LDS-staged coalesced epilogues.

typedef _Float16 f16;
typedef __attribute__((ext_vector_type(4))) _Float16 f16x4;
typedef __attribute__((ext_vector_type(8))) _Float16 f16x8;
typedef __attribute__((ext_vector_type(4))) float    f32x4;

#define BM 128
#define BN 128
#define BKH 64                      // K-tile in halfs (128 B rows)

#define SEQ   2048
#define DIM   768
#define NBAT  8
#define MTOT  (NBAT * SEQ)          // 16384
#define XN    ((long)MTOT * DIM)    // 12582912
#define WN    (DIM * DIM)           // 589824
#define SB    ((long)SEQ * SEQ)
#define QB    ((long)SEQ * DIM)
#define XN4   3145728               // XN/4
#define WN4   147456                // WN/4

__device__ __forceinline__ void async_cp16(const void* g, void* l) {
  __builtin_amdgcn_global_load_lds((__attribute__((address_space(1))) void*)g,
                                   (__attribute__((address_space(3))) void*)l,
                                   16, 0, 0);
}

// fp32 -> f16 for x and the three weights, one launch.
__global__ void cvt_all(const float* __restrict__ x, const float* __restrict__ wq,
                        const float* __restrict__ wk, const float* __restrict__ wv,
                        f16* __restrict__ out) {
  int i = blockIdx.x * 256 + threadIdx.x;      // float4 index
  const float* src; f16* dst; int idx;
  if (i < XN4) { src = x; dst = out; idx = i; }
  else {
    int j = i - XN4;
    int w = (j < WN4) ? 0 : (j < 2 * WN4) ? 1 : 2;
    idx = j - w * WN4;
    src = (w == 0) ? wq : (w == 1) ? wk : wv;
    dst = out + XN + (long)w * WN;
  }
  float4 v = ((const float4*)src)[idx];
  f16x4 o = {(f16)v.x, (f16)v.y, (f16)v.z, (f16)v.w};
  ((f16x4*)dst)[idx] = o;
}

// NT GEMM: C[m][n] = sum_k A[m][k]*B[n][k].
// MODE 0: f16 row-major out (Q,K; z selects W and C plane). SWAP=true.
// MODE 1: f16 out = exp(acc*scale) (unnormalized softmax numerator). SWAP=true.
// MODE 2: fp32 out = acc / rowsum(A) (PV with fused normalization). SWAP=true.
// MODE 3: f16 transposed out Vt[b][n][m-local]. SWAP=false.
// SWAP=true calls mfma(bf,af): lane&15 = m, regs = 4 consecutive n.
// SWAP=false: lane&15 = n, regs = 4 consecutive m (natural for transposed out).
template <int MODE, bool SWAP>
__global__ __launch_bounds__(256, 3)
void gemm_nt(const f16* __restrict__ Abase, long sAz,
             const f16* __restrict__ Bbase, long sBz,
             void* __restrict__ Cbase, long sCz,
             int N, int K, float scale)
{
  __shared__ __align__(16) char smem[34816];   // 32 KB staging, aliased epilogue
  f16* lA = (f16*)smem;                        // [128][64] halfs
  f16* lB = (f16*)(smem + 16384);

  const int tid  = threadIdx.x;
  const int z    = blockIdx.z;
  const int m0   = blockIdx.x * BM;
  const int n0   = blockIdx.y * BN;
  const int wave = tid >> 6;
  const int lane = tid & 63;
  const int wm   = (wave & 1) * 64;
  const int wn   = (wave >> 1) * 64;

  const f16* A = Abase + (long)z * sAz;
  const f16* B = Bbase + (long)z * sBz;

  f32x4 acc[4][4] = {};
  float rsum[4] = {0.f, 0.f, 0.f, 0.f};

  // staging: thread t loads 16B: row srow (of 32-row group p), swizzled k-chunk.
  const int srow = tid >> 3;                         // 0..31
  const int gcol = ((tid & 7) ^ (srow & 7)) * 8;     // swizzle chunk by row&7
  const f16* ga = A + (long)(m0 + srow) * K + gcol;
  const f16* gb = B + (long)(n0 + srow) * K + gcol;
  f16* la = lA + tid * 8;
  f16* lb = lB + tid * 8;

  // MFMA fragment addressing: row = lane&15 (+16i +wm), k-chunk (s*4+q)^swz
  const int frow = lane & 15;
  const int q    = lane >> 4;
  const int swz  = frow & 7;
  const int aro  = (wm + frow) * BKH;
  const int bro  = (wn + frow) * BKH;

  for (int k0 = 0; k0 < K; k0 += BKH) {
#pragma unroll
    for (int p = 0; p < 4; ++p) {
      async_cp16(ga + (long)(p * 32) * K + k0, la + p * 2048);
      async_cp16(gb + (long)(p * 32) * K + k0, lb + p * 2048);
    }
    __syncthreads();
#pragma unroll
    for (int s = 0; s < 2; ++s) {
      const int co = ((s * 4 + q) ^ swz) * 8;
      f16x8 af[4], bf[4];
#pragma unroll
      for (int i = 0; i < 4; ++i) af[i] = *(const f16x8*)&lA[aro + i * 1024 + co];
#pragma unroll
      for (int j = 0; j < 4; ++j) bf[j] = *(const f16x8*)&lB[bro + j * 1024 + co];
      if (MODE == 2) {  // accumulate row sums of A (= exp scores) in fp32
#pragma unroll
        for (int i = 0; i < 4; ++i) {
          float t = 0.f;
#pragma unroll
          for (int e = 0; e < 8; ++e) t += (float)af[i][e];
          rsum[i] += t;
        }
      }
#pragma unroll
      for (int i = 0; i < 4; ++i)
#pragma unroll
        for (int j = 0; j < 4; ++j)
          acc[i][j] = SWAP
            ? __builtin_amdgcn_mfma_f32_16x16x32_f16(bf[j], af[i], acc[i][j], 0, 0, 0)
            : __builtin_amdgcn_mfma_f32_16x16x32_f16(af[i], bf[j], acc[i][j], 0, 0, 0);
    }
    __syncthreads();   // frag reads done before next stage overwrites (also guards epilogue alias)
  }

  const int TS = 136;  // f16 epilogue tile stride (halfs): 272 B, 16B-aligned rows

  if constexpr (MODE == 0 || MODE == 1) {
    f16* T = (f16*)smem;   // [128][TS]
#pragma unroll
    for (int i = 0; i < 4; ++i)
#pragma unroll
      for (int j = 0; j < 4; ++j) {
        f16x4 v;
#pragma unroll
        for (int r = 0; r < 4; ++r) {
          float xv = acc[i][j][r];
          if (MODE == 1) xv = __expf(xv * scale);
          v[r] = (f16)xv;
        }
        *(f16x4*)&T[(wm + i * 16 + frow) * TS + wn + j * 16 + q * 4] = v;
      }
    __syncthreads();
    f16* C = (f16*)Cbase + (long)z * sCz;
    const int row = tid >> 1, seg = (tid & 1) * 64;
#pragma unroll
    for (int k = 0; k < 8; ++k) {
      f16x8 v = *(const f16x8*)&T[row * TS + seg + k * 8];
      *(f16x8*)&C[(long)(m0 + row) * N + n0 + seg + k * 8] = v;
    }
  }

  if constexpr (MODE == 3) {   // Vt[b][d][s], SWAP=false: regs = consecutive m (=s)
    f16* T = (f16*)smem;       // [n(=d) 128][TS] holding m(=s) contiguous
#pragma unroll
    for (int i = 0; i < 4; ++i)
#pragma unroll
      for (int j = 0; j < 4; ++j) {
        f16x4 v = {(f16)acc[i][j][0], (f16)acc[i][j][1],
                   (f16)acc[i][j][2], (f16)acc[i][j][3]};
        *(f16x4*)&T[(wn + j * 16 + frow) * TS + wm + i * 16 + q * 4] = v;
      }
    __syncthreads();
    f16* C = (f16*)Cbase;
    const int b = m0 >> 11, sl = m0 & 2047;
    const int row = tid >> 1, seg = (tid & 1) * 64;
#pragma unroll
    for (int k = 0; k < 8; ++k) {
      f16x8 v = *(const f16x8*)&T[row * TS + seg + k * 8];
      *(f16x8*)&C[(long)b * QB + (long)(n0 + row) * SEQ + sl + seg + k * 8] = v;
    }
  }

  if constexpr (MODE == 2) {   // fp32 out, normalized by rowsum; 2-pass (64 rows) epilogue
#pragma unroll
    for (int i = 0; i < 4; ++i) {
      rsum[i] += __shfl_xor(rsum[i], 16);
      rsum[i] += __shfl_xor(rsum[i], 32);   // full row sum for row wm+i*16+frow
    }
    float inv[4];
#pragma unroll
    for (int i = 0; i < 4; ++i) inv[i] = 1.0f / rsum[i];

    float* Tf = (float*)smem;   // [64][FS] fp32
    const int FS = 132;
    float* C = (float*)Cbase + (long)z * sCz;
    for (int pass = 0; pass < 2; ++pass) {
      if (wm == pass * 64) {
#pragma unroll
        for (int i = 0; i < 4; ++i)
#pragma unroll
          for (int j = 0; j < 4; ++j) {
            f32x4 v = acc[i][j] * inv[i];
            *(f32x4*)&Tf[(i * 16 + frow) * FS + wn + j * 16 + q * 4] = v;
          }
      }
      __syncthreads();
      const int row = tid >> 2, cs = (tid & 3) * 32;
#pragma unroll
      for (int k = 0; k < 8; ++k) {
        f32x4 v = *(const f32x4*)&Tf[row * FS + cs + k * 4];
        *(f32x4*)&C[(long)(m0 + pass * 64 + row) * N + n0 + cs + k * 4] = v;
      }
      if (pass == 0) __syncthreads();
    }
  }
}

extern "C" void kernel_launch(void* const* d_in, const int* in_sizes, int n_in,
                              void* d_out, int out_size, void* d_ws, size_t ws_size,
                              hipStream_t stream) {
  const float* x  = (const float*)d_in[0];
  const float* Wq = (const float*)d_in[1];
  const float* Wk = (const float*)d_in[2];
  const float* Wv = (const float*)d_in[3];

  f16* ws   = (f16*)d_ws;
  f16* x16  = ws;                  // XN
  f16* W16  = x16 + XN;            // 3*WN
  f16* Q16  = W16 + 3L * WN;       // XN
  f16* K16  = Q16 + XN;            // XN
  f16* Vt16 = K16 + XN;            // XN   [b][d][s]
  f16* S16  = Vt16 + XN;           // NBAT*SB  (exp scores, unnormalized)

  cvt_all<<<14016, 256, 0, stream>>>(x, Wq, Wk, Wv, ws);

  dim3 blk(256);
  // Q,K projections: z in {0,1}
  gemm_nt<0, true><<<dim3(MTOT / BM, DIM / BN, 2), blk, 0, stream>>>(
      x16, 0L, W16, (long)WN, (void*)Q16, XN, DIM, DIM, 1.0f);
  // V projection, transposed out
  gemm_nt<3, false><<<dim3(MTOT / BM, DIM / BN, 1), blk, 0, stream>>>(
      x16, 0L, W16 + 2L * WN, 0L, (void*)Vt16, 0L, DIM, DIM, 1.0f);
  // P' = exp(QK^T / sqrt(768)), f16, unnormalized
  gemm_nt<1, true><<<dim3(SEQ / BM, SEQ / BN, NBAT), blk, 0, stream>>>(
      Q16, QB, K16, QB, (void*)S16, SB, SEQ, DIM, 0.03608439182435161f);
  // H = P'V / rowsum(P'), fp32
  gemm_nt<2, true><<<dim3(SEQ / BM, DIM / BN, NBAT), blk, 0, stream>>>(
      S16, SB, Vt16, QB, d_out, QB, DIM, SEQ, 1.0f);
}